// Round 14
// baseline (352.289 us; speedup 1.0000x reference)
//
#include <hip/hip_runtime.h>
#include <hip/hip_bf16.h>

#define NN   50000
#define NE   160000
#define DDIM 512
#define MPAD 50176          // 392 * 128
#define NB_SCAN 196         // ceil(NN/256)

typedef __attribute__((ext_vector_type(8))) short  short8;
typedef __attribute__((ext_vector_type(8))) unsigned short ushort8;
typedef __attribute__((ext_vector_type(4))) float  f32x4;

__device__ __forceinline__ unsigned short f2bf(float f) {
  union { float f; unsigned u; } v; v.f = f;
  unsigned u = v.u;
  unsigned r = (u + 0x7FFFu + ((u >> 16) & 1u)) >> 16;   // RNE
  return (unsigned short)r;
}
__device__ __forceinline__ float bf2f(unsigned short s) {
  union { unsigned u; float f; } v; v.u = ((unsigned)s) << 16;
  return v.f;
}
__device__ __forceinline__ void unpack8(uint4 v, float* t) {
  t[0] = bf2f(v.x & 0xffff); t[1] = bf2f(v.x >> 16);
  t[2] = bf2f(v.y & 0xffff); t[3] = bf2f(v.y >> 16);
  t[4] = bf2f(v.z & 0xffff); t[5] = bf2f(v.z >> 16);
  t[6] = bf2f(v.w & 0xffff); t[7] = bf2f(v.w >> 16);
}

// ---------------- fused prep: cvt_x + cvt_w (both) + cnt zero ----------------
__global__ __launch_bounds__(256) void k_prep(
    const float* __restrict__ x, const float* __restrict__ W1,
    const float* __restrict__ W2, unsigned short* __restrict__ xb,
    unsigned short* __restrict__ Wt1, unsigned short* __restrict__ Wt2,
    int* __restrict__ cnt)
{
  int stride = gridDim.x * 256;
  int g0 = blockIdx.x * 256 + threadIdx.x;
  for (size_t t = g0; t < (size_t)MPAD * 64; t += stride) {
    ushort8 o;
    if (t * 8 < (size_t)NN * DDIM) {
      const float4* xp = (const float4*)x;
      float4 a = xp[t * 2], b = xp[t * 2 + 1];
      o[0] = f2bf(a.x); o[1] = f2bf(a.y); o[2] = f2bf(a.z); o[3] = f2bf(a.w);
      o[4] = f2bf(b.x); o[5] = f2bf(b.y); o[6] = f2bf(b.z); o[7] = f2bf(b.w);
    } else {
      #pragma unroll
      for (int j = 0; j < 8; ++j) o[j] = 0;
    }
    *(ushort8*)(xb + t * 8) = o;
  }
  for (int t = g0; t < DDIM * DDIM; t += stride) {
    int k = t >> 9, n = t & 511;
    Wt1[n * 512 + k] = f2bf(W1[t]);
    Wt2[n * 512 + k] = f2bf(W2[t]);
  }
  for (int i = g0; i < NN; i += stride) cnt[i] = 0;
}

// ---------------- graph build ----------------
__global__ void k_deg(const int* __restrict__ ei, int* __restrict__ cnt,
                      int* __restrict__ pos) {
  int e = blockIdx.x * 256 + threadIdx.x;
  if (e < NE) {
    int d = ei[NE + e];
    pos[e] = atomicAdd(&cnt[d], 1);
  }
}

__global__ void k_scan1(const int* __restrict__ cnt, int* __restrict__ bsum) {
  __shared__ int sd[256];
  int t = threadIdx.x;
  int i = blockIdx.x * 256 + t;
  sd[t] = (i < NN) ? cnt[i] : 0;
  __syncthreads();
  for (int off = 128; off > 0; off >>= 1) {
    if (t < off) sd[t] += sd[t + off];
    __syncthreads();
  }
  if (t == 0) bsum[blockIdx.x] = sd[0];
}

__global__ void k_scan2(const int* __restrict__ bsum, int* __restrict__ boff,
                        int* __restrict__ rowstart) {
  __shared__ int sd[256];
  int t = threadIdx.x;
  int v = (t < NB_SCAN) ? bsum[t] : 0;
  int x = v;
  sd[t] = x;
  __syncthreads();
  for (int off = 1; off < 256; off <<= 1) {
    int u = (t >= off) ? sd[t - off] : 0;
    __syncthreads();
    x += u; sd[t] = x;
    __syncthreads();
  }
  if (t < NB_SCAN) boff[t] = x - v;
  if (t == 0) rowstart[NN] = NE;
}

__global__ void k_scan3(const int* __restrict__ cnt, const int* __restrict__ boff,
                        int* __restrict__ rowstart) {
  __shared__ int sd[256];
  int t = threadIdx.x;
  int i = blockIdx.x * 256 + t;
  int v = (i < NN) ? cnt[i] : 0;
  int x = v;
  sd[t] = x;
  __syncthreads();
  for (int off = 1; off < 256; off <<= 1) {
    int u = (t >= off) ? sd[t - off] : 0;
    __syncthreads();
    x += u; sd[t] = x;
    __syncthreads();
  }
  if (i < NN) rowstart[i] = boff[blockIdx.x] + x - v;
}

__global__ void k_fill(const int* __restrict__ ei, const float* __restrict__ ea,
                       const int* __restrict__ rowstart, const int* __restrict__ pos,
                       int2* __restrict__ csre) {
  int e = blockIdx.x * 256 + threadIdx.x;
  if (e < NE) {
    int d = ei[NE + e];
    int p = rowstart[d] + pos[e];
    csre[p] = make_int2(ei[e], __float_as_int(ea[e]));
  }
}

__global__ void k_dis(const int* __restrict__ rowstart, const int2* __restrict__ csre,
                      float* __restrict__ dis1, float* __restrict__ dis2) {
  int i = blockIdx.x * 256 + threadIdx.x;
  if (i < NN) {
    int p0 = rowstart[i], p1 = rowstart[i + 1];
    float s = 1.0f;
    for (int p = p0; p < p1; ++p) s += __int_as_float(csre[p].y);
    dis1[i] = rsqrtf(s);
    dis2[i] = rsqrtf(1.0f + (float)(p1 - p0));
  }
}

__global__ void k_epre(const int2* __restrict__ csre, const float* __restrict__ dis1,
                       const float* __restrict__ dis2, int2* __restrict__ e1,
                       int2* __restrict__ e2) {
  int e = blockIdx.x * 256 + threadIdx.x;
  if (e < NE) {
    int2 pr = csre[e];
    int s = pr.x;
    float w = __int_as_float(pr.y);
    e1[e] = make_int2(s, __float_as_int(w * dis1[s]));
    e2[e] = make_int2(s, __float_as_int(dis2[s]));
  }
}

// ---------------- GEMM: resident-B streaming (ZERO in-loop barriers) --------
// BM=128, BN=64, block 512 thr = 8 waves (4M x 2N), wave tile 32x32.
// B-slice [64][512] bf16 = 64 KB staged ONCE into LDS (reg->swizzled ds_write,
// one __syncthreads total). A streams global->reg directly: per kt, 4 coalesced
// A-loads (wave covers 16 rows x 64B) + 4 swizzled B ds_reads + 8 MFMA, and the
// fully-unrolled kt loop has NO barriers -> compiler pipelines loads across kt
// freely; 2 blocks/CU (64KB LDS) x 8 waves = 16 waves/CU TLP.
// All 8 prior LDS-staged rendezvous schedules pinned at ~59us; this removes
// the rendezvous itself. XCD chunking: 3136 = 8*392, bcol fastest (8 bcol
// neighbors share each A-panel in XCD L2).
__global__ __launch_bounds__(512) void k_gemm(
    const unsigned short* __restrict__ A,   // [MPAD][512] bf16 row-major
    const unsigned short* __restrict__ B,   // [512][512] bf16, n-major
    unsigned short* __restrict__ C,         // [Mvalid][512] bf16
    int Mvalid)
{
  __shared__ unsigned short Bs[64 * 512];   // 64 KB

  int nwg  = gridDim.x;                     // 3136, divisible by 8
  int orig = blockIdx.x;
  int wgid = (orig & 7) * (nwg >> 3) + (orig >> 3);
  int bcol = (wgid & 7) * 64;               // N/64 = 8, fastest
  int brow = (wgid >> 3) * 128;

  int tid  = threadIdx.x;
  int lane = tid & 63;
  int wave = tid >> 6;
  int wr = wave >> 1, wc = wave & 1;        // 4M x 2N -> wave tile 32x32
  int r16 = lane & 15;
  int k8  = (lane >> 4) * 8;                // element k-offset of lane group
  int kl16 = (lane >> 4) * 16;              // same, bytes

  // one-time B stage: 4096 x 16B chunks, 8/thread; swizzle byte col by row
  // (same proven XOR family: rows 0-7 spread across 8 bank groups; rows r and
  //  r+8 alias = 2-way = free).
  #pragma unroll
  for (int i = 0; i < 8; ++i) {
    int c   = tid + (i << 9);               // 0..4095
    int row = c >> 6;                       // 0..63
    int kc  = c & 63;                       // 16B chunk within row
    uint4 v = *(const uint4*)(B + (size_t)(bcol + row) * 512 + kc * 8);
    *(uint4*)((char*)Bs + row * 1024 + ((kc << 4) ^ ((row & 7) << 4))) = v;
  }
  __syncthreads();                          // the ONLY barrier in the kernel

  const f32x4 zero = {0.f, 0.f, 0.f, 0.f};
  f32x4 acc[2][2];
  #pragma unroll
  for (int m = 0; m < 2; ++m)
    #pragma unroll
    for (int n = 0; n < 2; ++n) acc[m][n] = zero;

  // A fragment base: row = brow + wr*32 + m*16 + r16, k = kt*64 + ks*32 + k8
  const unsigned short* Ab = A + (size_t)(brow + wr * 32 + r16) * 512 + k8;

  #pragma unroll
  for (int kt = 0; kt < 8; ++kt) {
    short8 af[2][2], bfr[2][2];
    #pragma unroll
    for (int m = 0; m < 2; ++m)
      #pragma unroll
      for (int ks = 0; ks < 2; ++ks)
        af[m][ks] = *(const short8*)(Ab + (size_t)(m * 16) * 512 + kt * 64 + ks * 32);
    #pragma unroll
    for (int n = 0; n < 2; ++n) {
      int row = wc * 32 + n * 16 + r16;
      #pragma unroll
      for (int ks = 0; ks < 2; ++ks)
        bfr[n][ks] = *(const short8*)((const char*)Bs + row * 1024 +
                       ((kt * 128 + ks * 64 + kl16) ^ ((row & 7) << 4)));
    }
    #pragma unroll
    for (int ks = 0; ks < 2; ++ks)
      #pragma unroll
      for (int m = 0; m < 2; ++m)
        #pragma unroll
        for (int n = 0; n < 2; ++n)
          acc[m][n] = __builtin_amdgcn_mfma_f32_16x16x32_bf16(af[m][ks], bfr[n][ks], acc[m][n], 0, 0, 0);
  }

  int rbase = (lane >> 4) * 4;   // C/D: col=lane&15, row=(lane>>4)*4+reg
  int ccol  = lane & 15;
  #pragma unroll
  for (int m = 0; m < 2; ++m)
    #pragma unroll
    for (int n = 0; n < 2; ++n)
      #pragma unroll
      for (int i = 0; i < 4; ++i) {
        int grow = brow + wr * 32 + m * 16 + rbase + i;
        if (grow < Mvalid) {
          int gcol = bcol + wc * 32 + n * 16 + ccol;
          C[(size_t)grow * 512 + gcol] = f2bf(acc[m][n][i]);
        }
      }
}

// ---------------- aggregation: out[i] = b + dis_i^2*h[i] + sum_e c_e*h[s_e] ----
__global__ __launch_bounds__(256) void k_agg(
    const unsigned short* __restrict__ h, const float* __restrict__ dis,
    const float* __restrict__ bias, const int* __restrict__ rowstart,
    const int2* __restrict__ ep, void* __restrict__ outp, int outBf16)
{
  int node = blockIdx.x * 4 + (threadIdx.x >> 6);
  int lane = threadIdx.x & 63;
  if (node >= NN) return;                  // xb pad rows stay zero from k_prep
  const uint4* hp = (const uint4*)h;
  const float4* bp = (const float4*)bias;
  float4 b0 = bp[lane * 2], b1 = bp[lane * 2 + 1];
  float di = dis[node];
  int p0 = rowstart[node], p1 = rowstart[node + 1];
  uint4 hv = hp[(size_t)node * 64 + lane];
  float t0[8], t1[8], t2[8], t3[8], acc[8];
  unpack8(hv, t0);
  float selfc = di * di;
  #pragma unroll
  for (int j = 0; j < 8; ++j) acc[j] = t0[j] * selfc;
  int p = p0;
  for (; p + 4 <= p1; p += 4) {
    int2 e0 = ep[p], e1v = ep[p + 1], e2v = ep[p + 2], e3v = ep[p + 3];
    uint4 v0 = hp[(size_t)e0.x  * 64 + lane];
    uint4 v1 = hp[(size_t)e1v.x * 64 + lane];
    uint4 v2 = hp[(size_t)e2v.x * 64 + lane];
    uint4 v3 = hp[(size_t)e3v.x * 64 + lane];
    float c0 = __int_as_float(e0.y)  * di;
    float c1 = __int_as_float(e1v.y) * di;
    float c2 = __int_as_float(e2v.y) * di;
    float c3 = __int_as_float(e3v.y) * di;
    unpack8(v0, t0); unpack8(v1, t1); unpack8(v2, t2); unpack8(v3, t3);
    #pragma unroll
    for (int j = 0; j < 8; ++j) acc[j] += c0 * t0[j];
    #pragma unroll
    for (int j = 0; j < 8; ++j) acc[j] += c1 * t1[j];
    #pragma unroll
    for (int j = 0; j < 8; ++j) acc[j] += c2 * t2[j];
    #pragma unroll
    for (int j = 0; j < 8; ++j) acc[j] += c3 * t3[j];
  }
  for (; p + 2 <= p1; p += 2) {
    int2 e0 = ep[p], e1v = ep[p + 1];
    uint4 v0 = hp[(size_t)e0.x  * 64 + lane];
    uint4 v1 = hp[(size_t)e1v.x * 64 + lane];
    float c0 = __int_as_float(e0.y)  * di;
    float c1 = __int_as_float(e1v.y) * di;
    unpack8(v0, t0); unpack8(v1, t1);
    #pragma unroll
    for (int j = 0; j < 8; ++j) acc[j] += c0 * t0[j];
    #pragma unroll
    for (int j = 0; j < 8; ++j) acc[j] += c1 * t1[j];
  }
  if (p < p1) {
    int2 e0 = ep[p];
    uint4 v0 = hp[(size_t)e0.x * 64 + lane];
    float c0 = __int_as_float(e0.y) * di;
    unpack8(v0, t0);
    #pragma unroll
    for (int j = 0; j < 8; ++j) acc[j] += c0 * t0[j];
  }
  acc[0] += b0.x; acc[1] += b0.y; acc[2] += b0.z; acc[3] += b0.w;
  acc[4] += b1.x; acc[5] += b1.y; acc[6] += b1.z; acc[7] += b1.w;
  if (outBf16) {
    ushort8 o;
    #pragma unroll
    for (int j = 0; j < 8; ++j) o[j] = f2bf(fmaxf(acc[j], 0.0f));
    *(ushort8*)((unsigned short*)outp + (size_t)node * 512 + lane * 8) = o;
  } else {
    float* op = (float*)outp + (size_t)node * 512 + lane * 8;
    f32x4 o0 = {acc[0], acc[1], acc[2], acc[3]};
    f32x4 o1 = {acc[4], acc[5], acc[6], acc[7]};
    __builtin_nontemporal_store(o0, (f32x4*)op);
    __builtin_nontemporal_store(o1, (f32x4*)(op + 4));
  }
}

// ---------------- workspace layout ----------------
constexpr size_t al(size_t x) { return (x + 255) & ~(size_t)255; }
constexpr size_t SZ_XB  = (size_t)MPAD * DDIM * 2;
constexpr size_t SZ_H   = (size_t)NN   * DDIM * 2;
constexpr size_t SZ_WT  = (size_t)DDIM * DDIM * 2;
constexpr size_t O_XB   = 0;
constexpr size_t O_H    = al(O_XB + SZ_XB);
constexpr size_t O_WT1  = al(O_H + SZ_H);
constexpr size_t O_WT2  = al(O_WT1 + SZ_WT);
constexpr size_t O_DIS1 = al(O_WT2 + SZ_WT);
constexpr size_t O_DIS2 = al(O_DIS1 + (size_t)NN * 4);
constexpr size_t O_CNT  = al(O_DIS2 + (size_t)NN * 4);
constexpr size_t O_RS   = al(O_CNT + (size_t)NN * 4);
constexpr size_t O_POS  = al(O_RS + (size_t)(NN + 1) * 4);
constexpr size_t O_CSRE = al(O_POS + (size_t)NE * 4);
constexpr size_t O_E1   = al(O_CSRE + (size_t)NE * 8);
constexpr size_t O_E2   = al(O_E1 + (size_t)NE * 8);
constexpr size_t O_BSUM = al(O_E2 + (size_t)NE * 8);
constexpr size_t O_BOFF = al(O_BSUM + (size_t)NB_SCAN * 4);
constexpr size_t WS_NEED = al(O_BOFF + (size_t)NB_SCAN * 4);

extern "C" void kernel_launch(void* const* d_in, const int* in_sizes, int n_in,
                              void* d_out, int out_size, void* d_ws, size_t ws_size,
                              hipStream_t stream) {
  const float* x  = (const float*)d_in[0];
  const int*   ei = (const int*)d_in[1];
  const float* ea = (const float*)d_in[2];
  const float* W1 = (const float*)d_in[3];
  const float* b1 = (const float*)d_in[4];
  const float* W2 = (const float*)d_in[5];
  const float* b2 = (const float*)d_in[6];
  if (ws_size < WS_NEED) return;

  char* ws = (char*)d_ws;
  unsigned short* xb   = (unsigned short*)(ws + O_XB);
  unsigned short* h    = (unsigned short*)(ws + O_H);
  unsigned short* Wt1  = (unsigned short*)(ws + O_WT1);
  unsigned short* Wt2  = (unsigned short*)(ws + O_WT2);
  float* dis1 = (float*)(ws + O_DIS1);
  float* dis2 = (float*)(ws + O_DIS2);
  int*   cnt  = (int*)(ws + O_CNT);
  int*   rs   = (int*)(ws + O_RS);
  int*   pos  = (int*)(ws + O_POS);
  int2*  csre = (int2*)(ws + O_CSRE);
  int2*  e1   = (int2*)(ws + O_E1);
  int2*  e2   = (int2*)(ws + O_E2);
  int*   bsum = (int*)(ws + O_BSUM);
  int*   boff = (int*)(ws + O_BOFF);

  k_prep <<<2048, 256, 0, stream>>>(x, W1, W2, xb, Wt1, Wt2, cnt);
  k_deg  <<<(NE + 255) / 256, 256, 0, stream>>>(ei, cnt, pos);
  k_scan1<<<NB_SCAN, 256, 0, stream>>>(cnt, bsum);
  k_scan2<<<1, 256, 0, stream>>>(bsum, boff, rs);
  k_scan3<<<NB_SCAN, 256, 0, stream>>>(cnt, boff, rs);
  k_fill <<<(NE + 255) / 256, 256, 0, stream>>>(ei, ea, rs, pos, csre);
  k_dis  <<<NB_SCAN, 256, 0, stream>>>(rs, csre, dis1, dis2);
  k_epre <<<(NE + 255) / 256, 256, 0, stream>>>(csre, dis1, dis2, e1, e2);

  int ngemm = (MPAD / 128) * (DDIM / 64);    // 392 * 8 = 3136
  // layer 1
  k_gemm<<<ngemm, 512, 0, stream>>>(xb, Wt1, h, NN);
  k_agg <<<(NN + 3) / 4, 256, 0, stream>>>(h, dis1, b1, rs, e1,
                                           (void*)xb, 1);        // relu->bf16 into xb
  // layer 2
  k_gemm<<<ngemm, 512, 0, stream>>>(xb, Wt2, h, NN);
  k_agg <<<(NN + 3) / 4, 256, 0, stream>>>(h, dis2, b2, rs, e2,
                                           d_out, 0);            // f32 final
}

// Round 15
// 220.828 us; speedup vs baseline: 1.5953x; 1.5953x over previous
//
#include <hip/hip_runtime.h>
#include <hip/hip_bf16.h>

#define NN   50000
#define NE   160000
#define DDIM 512
#define MPAD 50048          // 391 * 128
#define NB_SCAN 196         // ceil(NN/256)

typedef __attribute__((ext_vector_type(8))) short  short8;
typedef __attribute__((ext_vector_type(8))) unsigned short ushort8;
typedef __attribute__((ext_vector_type(4))) float  f32x4;

__device__ __forceinline__ unsigned short f2bf(float f) {
  union { float f; unsigned u; } v; v.f = f;
  unsigned u = v.u;
  unsigned r = (u + 0x7FFFu + ((u >> 16) & 1u)) >> 16;   // RNE
  return (unsigned short)r;
}
__device__ __forceinline__ float bf2f(unsigned short s) {
  union { unsigned u; float f; } v; v.u = ((unsigned)s) << 16;
  return v.f;
}
__device__ __forceinline__ void unpack8(uint4 v, float* t) {
  t[0] = bf2f(v.x & 0xffff); t[1] = bf2f(v.x >> 16);
  t[2] = bf2f(v.y & 0xffff); t[3] = bf2f(v.y >> 16);
  t[4] = bf2f(v.z & 0xffff); t[5] = bf2f(v.z >> 16);
  t[6] = bf2f(v.w & 0xffff); t[7] = bf2f(v.w >> 16);
}
__device__ __forceinline__ void gload_lds16(const void* g, void* l) {
  __builtin_amdgcn_global_load_lds(
      (const __attribute__((address_space(1))) unsigned int*)g,
      (__attribute__((address_space(3))) unsigned int*)l, 16, 0, 0);
}

// ---------------- fused prep: cvt_x + cvt_w (both) + cnt zero ----------------
__global__ __launch_bounds__(256) void k_prep(
    const float* __restrict__ x, const float* __restrict__ W1,
    const float* __restrict__ W2, unsigned short* __restrict__ xb,
    unsigned short* __restrict__ Wt1, unsigned short* __restrict__ Wt2,
    int* __restrict__ cnt)
{
  int stride = gridDim.x * 256;
  int g0 = blockIdx.x * 256 + threadIdx.x;
  for (size_t t = g0; t < (size_t)MPAD * 64; t += stride) {
    ushort8 o;
    if (t * 8 < (size_t)NN * DDIM) {
      const float4* xp = (const float4*)x;
      float4 a = xp[t * 2], b = xp[t * 2 + 1];
      o[0] = f2bf(a.x); o[1] = f2bf(a.y); o[2] = f2bf(a.z); o[3] = f2bf(a.w);
      o[4] = f2bf(b.x); o[5] = f2bf(b.y); o[6] = f2bf(b.z); o[7] = f2bf(b.w);
    } else {
      #pragma unroll
      for (int j = 0; j < 8; ++j) o[j] = 0;
    }
    *(ushort8*)(xb + t * 8) = o;
  }
  for (int t = g0; t < DDIM * DDIM; t += stride) {
    int k = t >> 9, n = t & 511;
    Wt1[n * 512 + k] = f2bf(W1[t]);
    Wt2[n * 512 + k] = f2bf(W2[t]);
  }
  for (int i = g0; i < NN; i += stride) cnt[i] = 0;
}

// ---------------- graph build ----------------
__global__ void k_deg(const int* __restrict__ ei, int* __restrict__ cnt,
                      int* __restrict__ pos) {
  int e = blockIdx.x * 256 + threadIdx.x;
  if (e < NE) {
    int d = ei[NE + e];
    pos[e] = atomicAdd(&cnt[d], 1);
  }
}

// proven 3-kernel scan (R2-R7). (R8's single-block scan was 94us; reverted.)
__global__ void k_scan1(const int* __restrict__ cnt, int* __restrict__ bsum) {
  __shared__ int sd[256];
  int t = threadIdx.x;
  int i = blockIdx.x * 256 + t;
  sd[t] = (i < NN) ? cnt[i] : 0;
  __syncthreads();
  for (int off = 128; off > 0; off >>= 1) {
    if (t < off) sd[t] += sd[t + off];
    __syncthreads();
  }
  if (t == 0) bsum[blockIdx.x] = sd[0];
}

__global__ void k_scan2(const int* __restrict__ bsum, int* __restrict__ boff,
                        int* __restrict__ rowstart) {
  __shared__ int sd[256];
  int t = threadIdx.x;
  int v = (t < NB_SCAN) ? bsum[t] : 0;
  int x = v;
  sd[t] = x;
  __syncthreads();
  for (int off = 1; off < 256; off <<= 1) {
    int u = (t >= off) ? sd[t - off] : 0;
    __syncthreads();
    x += u; sd[t] = x;
    __syncthreads();
  }
  if (t < NB_SCAN) boff[t] = x - v;
  if (t == 0) rowstart[NN] = NE;
}

__global__ void k_scan3(const int* __restrict__ cnt, const int* __restrict__ boff,
                        int* __restrict__ rowstart) {
  __shared__ int sd[256];
  int t = threadIdx.x;
  int i = blockIdx.x * 256 + t;
  int v = (i < NN) ? cnt[i] : 0;
  int x = v;
  sd[t] = x;
  __syncthreads();
  for (int off = 1; off < 256; off <<= 1) {
    int u = (t >= off) ? sd[t - off] : 0;
    __syncthreads();
    x += u; sd[t] = x;
    __syncthreads();
  }
  if (i < NN) rowstart[i] = boff[blockIdx.x] + x - v;
}

// CSR fill: packed {src, w-bits} per edge (one 8B load in consumers)
__global__ void k_fill(const int* __restrict__ ei, const float* __restrict__ ea,
                       const int* __restrict__ rowstart, const int* __restrict__ pos,
                       int2* __restrict__ csre) {
  int e = blockIdx.x * 256 + threadIdx.x;
  if (e < NE) {
    int d = ei[NE + e];
    int p = rowstart[d] + pos[e];
    csre[p] = make_int2(ei[e], __float_as_int(ea[e]));
  }
}

__global__ void k_dis(const int* __restrict__ rowstart, const int2* __restrict__ csre,
                      float* __restrict__ dis1, float* __restrict__ dis2) {
  int i = blockIdx.x * 256 + threadIdx.x;
  if (i < NN) {
    int p0 = rowstart[i], p1 = rowstart[i + 1];
    float s = 1.0f;
    for (int p = p0; p < p1; ++p) s += __int_as_float(csre[p].y);
    dis1[i] = rsqrtf(s);
    dis2[i] = rsqrtf(1.0f + (float)(p1 - p0));
  }
}

// per-edge coefficient precompute (3-deep load chain -> 2-deep in agg)
__global__ void k_epre(const int2* __restrict__ csre, const float* __restrict__ dis1,
                       const float* __restrict__ dis2, int2* __restrict__ e1,
                       int2* __restrict__ e2) {
  int e = blockIdx.x * 256 + threadIdx.x;
  if (e < NE) {
    int2 pr = csre[e];
    int s = pr.x;
    float w = __int_as_float(pr.y);
    e1[e] = make_int2(s, __float_as_int(w * dis1[s]));
    e2[e] = make_int2(s, __float_as_int(dis2[s]));
  }
}

// ---------------- GEMM: C[m][n] = sum_k A[m][k] * B[n][k], bf16 in/out, f32 acc ----
// PROVEN 58.7us config (R2 bench): single-buffered 2x16KB LDS, __syncthreads
// pair per K-step, global_load_lds width=16, rule-21 XOR swizzle, bijective XCD
// chunking with bcol fastest. NINE structural variants measured equal or worse
// (R3-R8, R12 8-phase, R13 barrier-free streaming) -> this is the floor for
// this shape (M=50K, N=K=512) in plain HIP on gfx950.
__global__ __launch_bounds__(256) void k_gemm(
    const unsigned short* __restrict__ A,   // [>=brow+128][512] bf16 row-major (M x K)
    const unsigned short* __restrict__ B,   // [512][512] bf16, n-major (N x K)
    unsigned short* __restrict__ C,         // [Mvalid][512] bf16
    int Mvalid)
{
  __shared__ unsigned short As[128 * 64];   // 16 KB
  __shared__ unsigned short Bs[128 * 64];   // 16 KB

  // bijective XCD swizzle (m204): nwg = gridDim.x, 8 XCDs
  int nwg  = gridDim.x;
  int orig = blockIdx.x;
  int q = nwg >> 3, r = nwg & 7;
  int xcd = orig & 7, xpos = orig >> 3;
  int wgid = (xcd < r ? xcd * (q + 1) : r * (q + 1) + (xcd - r) * q) + xpos;
  int bcol = (wgid & 3) * 128;              // N/128 = 4, fastest
  int brow = (wgid >> 2) * 128;

  int tid  = threadIdx.x;
  int lane = tid & 63;
  int wave = tid >> 6;
  int wr = wave >> 1, wc = wave & 1;        // 2x2 waves -> 64x64 each
  int r16 = lane & 15;
  int kl16 = (lane >> 4) * 16;              // byte offset of this lane-group's k8

  const f32x4 zero = {0.f, 0.f, 0.f, 0.f};
  f32x4 acc[4][4];
  #pragma unroll
  for (int m = 0; m < 4; ++m)
    #pragma unroll
    for (int n = 0; n < 4; ++n) acc[m][n] = zero;

  for (int kt = 0; kt < 512; kt += 64) {
    #pragma unroll
    for (int i = 0; i < 4; ++i) {
      int c   = tid + (i << 8);             // 0..1023
      int row = c >> 3;                     // 0..127
      int qo  = ((c & 7) << 4) ^ ((row & 7) << 4);   // logical byte col in [0,128)
      gload_lds16(A + (size_t)(brow + row) * 512 + kt + (qo >> 1),
                  (char*)As + (size_t)c * 16);
      gload_lds16(B + (size_t)(bcol + row) * 512 + kt + (qo >> 1),
                  (char*)Bs + (size_t)c * 16);
    }
    __syncthreads();

    #pragma unroll
    for (int ks = 0; ks < 2; ++ks) {
      short8 af[4], bfr[4];
      int qo = kl16 + ks * 64;              // logical byte col of fragment
      #pragma unroll
      for (int m = 0; m < 4; ++m) {
        int row = wr * 64 + m * 16 + r16;
        af[m] = *(const short8*)((const char*)As + row * 128 + (qo ^ ((row & 7) << 4)));
      }
      #pragma unroll
      for (int n = 0; n < 4; ++n) {
        int row = wc * 64 + n * 16 + r16;
        bfr[n] = *(const short8*)((const char*)Bs + row * 128 + (qo ^ ((row & 7) << 4)));
      }
      #pragma unroll
      for (int m = 0; m < 4; ++m)
        #pragma unroll
        for (int n = 0; n < 4; ++n)
          acc[m][n] = __builtin_amdgcn_mfma_f32_16x16x32_bf16(af[m], bfr[n], acc[m][n], 0, 0, 0);
    }
    __syncthreads();
  }

  int rbase = (lane >> 4) * 4;   // C/D: col=lane&15, row=(lane>>4)*4+reg
  int ccol  = lane & 15;
  #pragma unroll
  for (int m = 0; m < 4; ++m)
    #pragma unroll
    for (int n = 0; n < 4; ++n)
      #pragma unroll
      for (int i = 0; i < 4; ++i) {
        int grow = brow + wr * 64 + m * 16 + rbase + i;
        if (grow < Mvalid) {
          int gcol = bcol + wc * 64 + n * 16 + ccol;
          C[(size_t)grow * 512 + gcol] = f2bf(acc[m][n][i]);
        }
      }
}

// ---------------- aggregation: out[i] = b + dis_i^2*h[i] + sum_e c_e*h[s_e] ----
__global__ __launch_bounds__(256) void k_agg(
    const unsigned short* __restrict__ h, const float* __restrict__ dis,
    const float* __restrict__ bias, const int* __restrict__ rowstart,
    const int2* __restrict__ ep, void* __restrict__ outp, int outBf16)
{
  int node = blockIdx.x * 4 + (threadIdx.x >> 6);
  int lane = threadIdx.x & 63;
  if (node >= NN) return;                  // xb pad rows stay zero from k_prep
  const uint4* hp = (const uint4*)h;
  const float4* bp = (const float4*)bias;
  float4 b0 = bp[lane * 2], b1 = bp[lane * 2 + 1];
  float di = dis[node];
  int p0 = rowstart[node], p1 = rowstart[node + 1];
  uint4 hv = hp[(size_t)node * 64 + lane];
  float t0[8], t1[8], t2[8], t3[8], acc[8];
  unpack8(hv, t0);
  float selfc = di * di;
  #pragma unroll
  for (int j = 0; j < 8; ++j) acc[j] = t0[j] * selfc;
  int p = p0;
  for (; p + 4 <= p1; p += 4) {
    int2 e0 = ep[p], e1v = ep[p + 1], e2v = ep[p + 2], e3v = ep[p + 3];
    uint4 v0 = hp[(size_t)e0.x  * 64 + lane];
    uint4 v1 = hp[(size_t)e1v.x * 64 + lane];
    uint4 v2 = hp[(size_t)e2v.x * 64 + lane];
    uint4 v3 = hp[(size_t)e3v.x * 64 + lane];
    float c0 = __int_as_float(e0.y)  * di;
    float c1 = __int_as_float(e1v.y) * di;
    float c2 = __int_as_float(e2v.y) * di;
    float c3 = __int_as_float(e3v.y) * di;
    unpack8(v0, t0); unpack8(v1, t1); unpack8(v2, t2); unpack8(v3, t3);
    #pragma unroll
    for (int j = 0; j < 8; ++j) acc[j] += c0 * t0[j];
    #pragma unroll
    for (int j = 0; j < 8; ++j) acc[j] += c1 * t1[j];
    #pragma unroll
    for (int j = 0; j < 8; ++j) acc[j] += c2 * t2[j];
    #pragma unroll
    for (int j = 0; j < 8; ++j) acc[j] += c3 * t3[j];
  }
  for (; p + 2 <= p1; p += 2) {
    int2 e0 = ep[p], e1v = ep[p + 1];
    uint4 v0 = hp[(size_t)e0.x  * 64 + lane];
    uint4 v1 = hp[(size_t)e1v.x * 64 + lane];
    float c0 = __int_as_float(e0.y)  * di;
    float c1 = __int_as_float(e1v.y) * di;
    unpack8(v0, t0); unpack8(v1, t1);
    #pragma unroll
    for (int j = 0; j < 8; ++j) acc[j] += c0 * t0[j];
    #pragma unroll
    for (int j = 0; j < 8; ++j) acc[j] += c1 * t1[j];
  }
  if (p < p1) {
    int2 e0 = ep[p];
    uint4 v0 = hp[(size_t)e0.x * 64 + lane];
    float c0 = __int_as_float(e0.y) * di;
    unpack8(v0, t0);
    #pragma unroll
    for (int j = 0; j < 8; ++j) acc[j] += c0 * t0[j];
  }
  acc[0] += b0.x; acc[1] += b0.y; acc[2] += b0.z; acc[3] += b0.w;
  acc[4] += b1.x; acc[5] += b1.y; acc[6] += b1.z; acc[7] += b1.w;
  if (outBf16) {
    ushort8 o;
    #pragma unroll
    for (int j = 0; j < 8; ++j) o[j] = f2bf(fmaxf(acc[j], 0.0f));
    *(ushort8*)((unsigned short*)outp + (size_t)node * 512 + lane * 8) = o;
  } else {
    float* op = (float*)outp + (size_t)node * 512 + lane * 8;
    f32x4 o0 = {acc[0], acc[1], acc[2], acc[3]};
    f32x4 o1 = {acc[4], acc[5], acc[6], acc[7]};
    __builtin_nontemporal_store(o0, (f32x4*)op);
    __builtin_nontemporal_store(o1, (f32x4*)(op + 4));
  }
}

// ---------------- workspace layout ----------------
constexpr size_t al(size_t x) { return (x + 255) & ~(size_t)255; }
constexpr size_t SZ_XB  = (size_t)MPAD * DDIM * 2;
constexpr size_t SZ_H   = (size_t)NN   * DDIM * 2;
constexpr size_t SZ_WT  = (size_t)DDIM * DDIM * 2;
constexpr size_t O_XB   = 0;
constexpr size_t O_H    = al(O_XB + SZ_XB);
constexpr size_t O_WT1  = al(O_H + SZ_H);
constexpr size_t O_WT2  = al(O_WT1 + SZ_WT);
constexpr size_t O_DIS1 = al(O_WT2 + SZ_WT);
constexpr size_t O_DIS2 = al(O_DIS1 + (size_t)NN * 4);
constexpr size_t O_CNT  = al(O_DIS2 + (size_t)NN * 4);
constexpr size_t O_RS   = al(O_CNT + (size_t)NN * 4);
constexpr size_t O_POS  = al(O_RS + (size_t)(NN + 1) * 4);
constexpr size_t O_CSRE = al(O_POS + (size_t)NE * 4);
constexpr size_t O_E1   = al(O_CSRE + (size_t)NE * 8);
constexpr size_t O_E2   = al(O_E1 + (size_t)NE * 8);
constexpr size_t O_BSUM = al(O_E2 + (size_t)NE * 8);
constexpr size_t O_BOFF = al(O_BSUM + (size_t)NB_SCAN * 4);
constexpr size_t WS_NEED = al(O_BOFF + (size_t)NB_SCAN * 4);

extern "C" void kernel_launch(void* const* d_in, const int* in_sizes, int n_in,
                              void* d_out, int out_size, void* d_ws, size_t ws_size,
                              hipStream_t stream) {
  const float* x  = (const float*)d_in[0];
  const int*   ei = (const int*)d_in[1];
  const float* ea = (const float*)d_in[2];
  const float* W1 = (const float*)d_in[3];
  const float* b1 = (const float*)d_in[4];
  const float* W2 = (const float*)d_in[5];
  const float* b2 = (const float*)d_in[6];
  if (ws_size < WS_NEED) return;

  char* ws = (char*)d_ws;
  unsigned short* xb   = (unsigned short*)(ws + O_XB);
  unsigned short* h    = (unsigned short*)(ws + O_H);
  unsigned short* Wt1  = (unsigned short*)(ws + O_WT1);
  unsigned short* Wt2  = (unsigned short*)(ws + O_WT2);
  float* dis1 = (float*)(ws + O_DIS1);
  float* dis2 = (float*)(ws + O_DIS2);
  int*   cnt  = (int*)(ws + O_CNT);
  int*   rs   = (int*)(ws + O_RS);
  int*   pos  = (int*)(ws + O_POS);
  int2*  csre = (int2*)(ws + O_CSRE);
  int2*  e1   = (int2*)(ws + O_E1);
  int2*  e2   = (int2*)(ws + O_E2);
  int*   bsum = (int*)(ws + O_BSUM);
  int*   boff = (int*)(ws + O_BOFF);

  k_prep <<<2048, 256, 0, stream>>>(x, W1, W2, xb, Wt1, Wt2, cnt);
  k_deg  <<<(NE + 255) / 256, 256, 0, stream>>>(ei, cnt, pos);
  k_scan1<<<NB_SCAN, 256, 0, stream>>>(cnt, bsum);
  k_scan2<<<1, 256, 0, stream>>>(bsum, boff, rs);
  k_scan3<<<NB_SCAN, 256, 0, stream>>>(cnt, boff, rs);
  k_fill <<<(NE + 255) / 256, 256, 0, stream>>>(ei, ea, rs, pos, csre);
  k_dis  <<<NB_SCAN, 256, 0, stream>>>(rs, csre, dis1, dis2);
  k_epre <<<(NE + 255) / 256, 256, 0, stream>>>(csre, dis1, dis2, e1, e2);

  int ngemm = (MPAD / 128) * (DDIM / 128);   // 1564
  // layer 1
  k_gemm<<<ngemm, 256, 0, stream>>>(xb, Wt1, h, NN);
  k_agg <<<(NN + 3) / 4, 256, 0, stream>>>(h, dis1, b1, rs, e1,
                                           (void*)xb, 1);        // relu->bf16 into xb
  // layer 2
  k_gemm<<<ngemm, 256, 0, stream>>>(xb, Wt2, h, NN);
  k_agg <<<(NN + 3) / 4, 256, 0, stream>>>(h, dis2, b2, rs, e2,
                                           d_out, 0);            // f32 final
}